// Round 5
// baseline (20.518 us; speedup 1.0000x reference)
//
#include <hip/hip_runtime.h>
#include <math.h>

// Problem constants: B=16, N=1024, D=3
#define NPTS  1024
#define EPSF  1e-8f

// ws layout (floats):
//   [0, 512)    chamfer partial per block (even bid = dl, odd bid = dr)  -- all > 0
//   [512, 1024) side partial per block (even bid = diffusion, odd = emd) -- all > 0
#define OFF_PC 0
#define OFF_PS 512

__device__ __forceinline__ float clampf(float v, float lo, float hi) {
    return fminf(fmaxf(v, lo), hi);
}

// Single fused kernel, 512 blocks x 256 (all co-resident: 2 blocks/CU).
// dir = bid&1; rest = bid>>1 = batch*16 + 64-row chunk.
// Chamfer: strip s = tid&31 scans candidates j = 32k+s (stride-1 LDS, no pad);
// rowgroup g = tid>>5 holds R=8 rows in registers -> 32 ds_read_b128/thread.
// Block 0 then spin-waits for all 1024 strictly-positive partials (device
// scope) and performs the final combine -- no second dispatch, no grid sync.
__global__ __launch_bounds__(256) void kFused(
    const float* __restrict__ npred, const float* __restrict__ ntgt,
    const float* __restrict__ pp,    const float* __restrict__ tp,
    const int*   __restrict__ assign, float* __restrict__ ws,
    float* __restrict__ out) {
    const int bid  = blockIdx.x;
    const int dir  = bid & 1;
    const int rest = bid >> 1;
    const int b    = rest >> 4;
    const int c    = rest & 15;
    const int tid  = threadIdx.x;

    __shared__ float4 sec[NPTS];   // 16 KB, no pad (stride-1 reads)

    const float* secSrc = dir ? pp : tp;
    const float* firSrc = dir ? tp : pp;

    // Stage + clip + normalize second cloud (coalesced reads, stride-1 writes).
    const float* sbase = secSrc + b * 3072;
    #pragma unroll
    for (int m = 0; m < 4; ++m) {
        int q = (m << 8) + tid;
        float x = sbase[3 * q], y = sbase[3 * q + 1], z = sbase[3 * q + 2];
        x = clampf(x, -1.f, 1.f); y = clampf(y, -1.f, 1.f); z = clampf(z, -1.f, 1.f);
        float n = fmaxf(sqrtf(x * x + y * y + z * z), EPSF);
        float r = 1.0f / n;
        sec[q] = make_float4(x * r, y * r, z * r, 0.f);
    }

    // Side work (overlaps staging).
    float side = 0.f;
    if (dir == 0) {
        if (tid < 48) {   // diffusion: 48 float4 per dir0-block
            int idx = rest * 48 + tid;
            float4 a  = ((const float4*)npred)[idx];
            float4 bb = ((const float4*)ntgt)[idx];
            float d0 = a.x - bb.x, d1 = a.y - bb.y, d2 = a.z - bb.z, d3 = a.w - bb.w;
            side = d0 * d0 + d1 * d1 + d2 * d2 + d3 * d3;
        }
    } else {
        if (tid < 64) {   // EMD: 64 points per dir1-block
            int p    = rest * 64 + tid;
            int base = 3 * p;
            float px = pp[base], py = pp[base + 1], pz = pp[base + 2];
            int bb = p >> 10;
            int a  = assign[p];
            int qb = 3 * ((bb << 10) + a);
            float mx = tp[qb], my = tp[qb + 1], mz = tp[qb + 2];
            float ex = clampf(px, -2.f, 2.f) - clampf(mx, -2.f, 2.f);
            float ey = clampf(py, -2.f, 2.f) - clampf(my, -2.f, 2.f);
            float ez = clampf(pz, -2.f, 2.f) - clampf(mz, -2.f, 2.f);
            side = fmaxf(sqrtf(ex * ex + ey * ey + ez * ez), EPSF);
        }
    }

    // My 8 rows: rows c*64 + g*8 .. +7 -> 24 consecutive floats (6 float4).
    const int s = tid & 31;
    const int g = tid >> 5;
    const float4* fb4 = (const float4*)(firSrc + b * 3072 + 192 * c + 24 * g);
    float4 rv0 = fb4[0], rv1 = fb4[1], rv2 = fb4[2];
    float4 rv3 = fb4[3], rv4 = fb4[4], rv5 = fb4[5];

    float fx[8], fy[8], fz[8];
    {
        float rx[8] = { rv0.x, rv0.w, rv1.z, rv2.y, rv3.x, rv3.w, rv4.z, rv5.y };
        float ry[8] = { rv0.y, rv1.x, rv1.w, rv2.z, rv3.y, rv4.x, rv4.w, rv5.z };
        float rz[8] = { rv0.z, rv1.y, rv2.x, rv2.w, rv3.z, rv4.y, rv5.x, rv5.w };
        #pragma unroll
        for (int r = 0; r < 8; ++r) {
            float x = clampf(rx[r], -1.f, 1.f);
            float y = clampf(ry[r], -1.f, 1.f);
            float z = clampf(rz[r], -1.f, 1.f);
            float n = fmaxf(sqrtf(x * x + y * y + z * z), EPSF);
            float rr = 1.f / n;
            fx[r] = x * rr; fy[r] = y * rr; fz[r] = z * rr;
        }
    }

    __syncthreads();

    // Scan strip j = 32k + s (lanes stride-1). min||a-b||^2 = 2 - 2*max(dot).
    float m[8];
    #pragma unroll
    for (int r = 0; r < 8; ++r) m[r] = -4.f;
    #pragma unroll 4
    for (int k = 0; k < 32; ++k) {
        float4 g4 = sec[(k << 5) + s];
        #pragma unroll
        for (int r = 0; r < 8; ++r)
            m[r] = fmaxf(m[r], fmaf(fx[r], g4.x, fmaf(fy[r], g4.y, fz[r] * g4.z)));
    }
    // Reduce over 32 strip-lanes (xor o<=16 stays within each 32-lane half).
    #pragma unroll
    for (int o = 1; o < 32; o <<= 1) {
        #pragma unroll
        for (int r = 0; r < 8; ++r) m[r] = fmaxf(m[r], __shfl_xor(m[r], o, 64));
    }

    float val = 0.f;
    if (s == 0) {
        #pragma unroll
        for (int r = 0; r < 8; ++r) {
            float ss   = fmaxf(2.f - 2.f * m[r], 0.f);
            float dist = fmaxf(sqrtf(ss), EPSF);
            float ld   = clampf(logf(dist + EPSF), -10.f, 10.f);
            val += expf(ld);
        }
    }

    // Deterministic block reduction of (val, side).
    for (int o = 32; o; o >>= 1) {
        val  += __shfl_down(val,  o, 64);
        side += __shfl_down(side, o, 64);
    }
    __shared__ float sv[4], sw[4];
    int w = tid >> 6;
    if ((tid & 63) == 0) { sv[w] = val; sw[w] = side; }
    __syncthreads();
    if (tid == 0) {
        __hip_atomic_store(&ws[OFF_PC + bid], sv[0] + sv[1] + sv[2] + sv[3],
                           __ATOMIC_RELEASE, __HIP_MEMORY_SCOPE_AGENT);
        __hip_atomic_store(&ws[OFF_PS + bid], sw[0] + sw[1] + sw[2] + sw[3],
                           __ATOMIC_RELEASE, __HIP_MEMORY_SCOPE_AGENT);
    }

    if (bid != 0) return;

    // Block 0: spin until all partials are > 0 (poison 0xAA.. < 0, zero <= 0),
    // then combine. Replays may see stale-but-bit-identical values -- benign.
    float dl, dr, sd, se;
    long spin = 0;
    do {
        dl = __hip_atomic_load(&ws[OFF_PC + 2 * tid],     __ATOMIC_ACQUIRE, __HIP_MEMORY_SCOPE_AGENT);
        dr = __hip_atomic_load(&ws[OFF_PC + 2 * tid + 1], __ATOMIC_ACQUIRE, __HIP_MEMORY_SCOPE_AGENT);
        sd = __hip_atomic_load(&ws[OFF_PS + 2 * tid],     __ATOMIC_ACQUIRE, __HIP_MEMORY_SCOPE_AGENT);
        se = __hip_atomic_load(&ws[OFF_PS + 2 * tid + 1], __ATOMIC_ACQUIRE, __HIP_MEMORY_SCOPE_AGENT);
        if (dl > 0.f && dr > 0.f && sd > 0.f && se > 0.f) break;
        __builtin_amdgcn_s_sleep(2);
    } while (++spin < (1L << 26));   // hang insurance

    for (int o = 32; o; o >>= 1) {
        dl += __shfl_down(dl, o, 64);
        dr += __shfl_down(dr, o, 64);
        sd += __shfl_down(sd, o, 64);
        se += __shfl_down(se, o, 64);
    }
    __shared__ float rr2[4][4];
    if ((tid & 63) == 0) { rr2[w][0] = dl; rr2[w][1] = dr; rr2[w][2] = sd; rr2[w][3] = se; }
    __syncthreads();
    if (tid == 0) {
        float Sl = rr2[0][0] + rr2[1][0] + rr2[2][0] + rr2[3][0];
        float Sr = rr2[0][1] + rr2[1][1] + rr2[2][1] + rr2[3][1];
        float Sd = rr2[0][2] + rr2[1][2] + rr2[2][2] + rr2[3][2];
        float Se = rr2[0][3] + rr2[1][3] + rr2[2][3] + rr2[3][3];
        float diffusion = Sd * (1.0f / 49152.0f);
        float cd        = 0.5f * (Sl + Sr) * (1.0f / 16384.0f);
        float emd       = Se * (1.0f / 16384.0f);
        out[0] = diffusion + 0.1f * cd + 0.05f * emd;
    }
}

extern "C" void kernel_launch(void* const* d_in, const int* in_sizes, int n_in,
                              void* d_out, int out_size, void* d_ws, size_t ws_size,
                              hipStream_t stream) {
    const float* npred  = (const float*)d_in[0];
    const float* ntgt   = (const float*)d_in[1];
    const float* pp     = (const float*)d_in[2];
    const float* tp     = (const float*)d_in[3];
    const int*   assign = (const int*)d_in[4];
    float* ws  = (float*)d_ws;
    float* out = (float*)d_out;

    hipLaunchKernelGGL(kFused, dim3(512), dim3(256), 0, stream,
                       npred, ntgt, pp, tp, assign, ws, out);
}

// Round 6
// 15.314 us; speedup vs baseline: 1.3398x; 1.3398x over previous
//
#include <hip/hip_runtime.h>
#include <math.h>

// Problem constants: B=16, N=1024, D=3
#define NPTS  1024
#define EPSF  1e-8f

// ws layout (floats):
//   [0, 512)    chamfer partial per block (even bid = dl, odd bid = dr)
//   [512, 1024) side partial per block (even bid = diffusion, odd bid = emd)
#define OFF_PC 0
#define OFF_PS 512

__device__ __forceinline__ float clampf(float v, float lo, float hi) {
    return fminf(fmaxf(v, lo), hi);
}

// Main kernel: chamfer (R=8 register row-blocking) + side work.
// grid = 512: dir = bid&1; rest = bid>>1 = batch*16 + 64-row chunk.
// strip s = tid&31 scans candidates j = 32k+s (stride-1 LDS, conflict-free);
// rowgroup g = tid>>5 holds 8 rows in registers -> 32 ds_read_b128/thread,
// each feeding 32 VALU ops.
__global__ __launch_bounds__(256) void kMain(
    const float* __restrict__ npred, const float* __restrict__ ntgt,
    const float* __restrict__ pp,    const float* __restrict__ tp,
    const int*   __restrict__ assign, float* __restrict__ ws) {
    const int bid  = blockIdx.x;
    const int dir  = bid & 1;
    const int rest = bid >> 1;
    const int b    = rest >> 4;
    const int c    = rest & 15;
    const int tid  = threadIdx.x;

    __shared__ float4 sec[NPTS];   // 16 KB, no pad (stride-1 reads)

    const float* secSrc = dir ? pp : tp;
    const float* firSrc = dir ? tp : pp;

    // Stage + clip + normalize second cloud (coalesced reads, stride-1 writes).
    const float* sbase = secSrc + b * 3072;
    #pragma unroll
    for (int m = 0; m < 4; ++m) {
        int q = (m << 8) + tid;
        float x = sbase[3 * q], y = sbase[3 * q + 1], z = sbase[3 * q + 2];
        x = clampf(x, -1.f, 1.f); y = clampf(y, -1.f, 1.f); z = clampf(z, -1.f, 1.f);
        float n = fmaxf(sqrtf(x * x + y * y + z * z), EPSF);
        float r = 1.0f / n;
        sec[q] = make_float4(x * r, y * r, z * r, 0.f);
    }

    // Side work (overlaps staging).
    float side = 0.f;
    if (dir == 0) {
        if (tid < 48) {   // diffusion: 48 float4 per dir0-block
            int idx = rest * 48 + tid;
            float4 a  = ((const float4*)npred)[idx];
            float4 bb = ((const float4*)ntgt)[idx];
            float d0 = a.x - bb.x, d1 = a.y - bb.y, d2 = a.z - bb.z, d3 = a.w - bb.w;
            side = d0 * d0 + d1 * d1 + d2 * d2 + d3 * d3;
        }
    } else {
        if (tid < 64) {   // EMD: 64 points per dir1-block
            int p    = rest * 64 + tid;
            int base = 3 * p;
            float px = pp[base], py = pp[base + 1], pz = pp[base + 2];
            int bb = p >> 10;
            int a  = assign[p];
            int qb = 3 * ((bb << 10) + a);
            float mx = tp[qb], my = tp[qb + 1], mz = tp[qb + 2];
            float ex = clampf(px, -2.f, 2.f) - clampf(mx, -2.f, 2.f);
            float ey = clampf(py, -2.f, 2.f) - clampf(my, -2.f, 2.f);
            float ez = clampf(pz, -2.f, 2.f) - clampf(mz, -2.f, 2.f);
            side = fmaxf(sqrtf(ex * ex + ey * ey + ez * ez), EPSF);
        }
    }

    // My 8 rows: rows c*64 + g*8 .. +7 -> 24 consecutive floats (6 float4).
    const int s = tid & 31;
    const int g = tid >> 5;
    const float4* fb4 = (const float4*)(firSrc + b * 3072 + 192 * c + 24 * g);
    float4 rv0 = fb4[0], rv1 = fb4[1], rv2 = fb4[2];
    float4 rv3 = fb4[3], rv4 = fb4[4], rv5 = fb4[5];

    float fx[8], fy[8], fz[8];
    {
        float rx[8] = { rv0.x, rv0.w, rv1.z, rv2.y, rv3.x, rv3.w, rv4.z, rv5.y };
        float ry[8] = { rv0.y, rv1.x, rv1.w, rv2.z, rv3.y, rv4.x, rv4.w, rv5.z };
        float rz[8] = { rv0.z, rv1.y, rv2.x, rv2.w, rv3.z, rv4.y, rv5.x, rv5.w };
        #pragma unroll
        for (int r = 0; r < 8; ++r) {
            float x = clampf(rx[r], -1.f, 1.f);
            float y = clampf(ry[r], -1.f, 1.f);
            float z = clampf(rz[r], -1.f, 1.f);
            float n = fmaxf(sqrtf(x * x + y * y + z * z), EPSF);
            float rr = 1.f / n;
            fx[r] = x * rr; fy[r] = y * rr; fz[r] = z * rr;
        }
    }

    __syncthreads();

    // Scan strip j = 32k + s (lanes stride-1). min||a-b||^2 = 2 - 2*max(dot).
    float m[8];
    #pragma unroll
    for (int r = 0; r < 8; ++r) m[r] = -4.f;
    #pragma unroll 4
    for (int k = 0; k < 32; ++k) {
        float4 g4 = sec[(k << 5) + s];
        #pragma unroll
        for (int r = 0; r < 8; ++r)
            m[r] = fmaxf(m[r], fmaf(fx[r], g4.x, fmaf(fy[r], g4.y, fz[r] * g4.z)));
    }
    // Reduce over the 32 strip-lanes.
    #pragma unroll
    for (int o = 1; o < 32; o <<= 1) {
        #pragma unroll
        for (int r = 0; r < 8; ++r) m[r] = fmaxf(m[r], __shfl_xor(m[r], o, 64));
    }

    float val = 0.f;
    if (s == 0) {
        #pragma unroll
        for (int r = 0; r < 8; ++r) {
            float ss   = fmaxf(2.f - 2.f * m[r], 0.f);
            float dist = fmaxf(sqrtf(ss), EPSF);
            float ld   = clampf(logf(dist + EPSF), -10.f, 10.f);
            val += expf(ld);
        }
    }

    // Deterministic block reduction of (val, side) -> ws partials.
    for (int o = 32; o; o >>= 1) {
        val  += __shfl_down(val,  o, 64);
        side += __shfl_down(side, o, 64);
    }
    __shared__ float sv[4], sw[4];
    int w = tid >> 6;
    if ((tid & 63) == 0) { sv[w] = val; sw[w] = side; }
    __syncthreads();
    if (tid == 0) {
        ws[OFF_PC + bid] = sv[0] + sv[1] + sv[2] + sv[3];
        ws[OFF_PS + bid] = sw[0] + sw[1] + sw[2] + sw[3];
    }
}

// Final deterministic combine.
__global__ __launch_bounds__(256) void kC(const float* __restrict__ ws,
                                          float* __restrict__ out) {
    const int tid = threadIdx.x;
    float dl = ws[OFF_PC + 2 * tid];
    float dr = ws[OFF_PC + 2 * tid + 1];
    float sd = ws[OFF_PS + 2 * tid];
    float se = ws[OFF_PS + 2 * tid + 1];

    for (int o = 32; o; o >>= 1) {
        dl += __shfl_down(dl, o, 64);
        dr += __shfl_down(dr, o, 64);
        sd += __shfl_down(sd, o, 64);
        se += __shfl_down(se, o, 64);
    }
    __shared__ float rr[4][4];
    int w = tid >> 6;
    if ((tid & 63) == 0) { rr[w][0] = dl; rr[w][1] = dr; rr[w][2] = sd; rr[w][3] = se; }
    __syncthreads();
    if (tid == 0) {
        float Sl = rr[0][0] + rr[1][0] + rr[2][0] + rr[3][0];
        float Sr = rr[0][1] + rr[1][1] + rr[2][1] + rr[3][1];
        float Sd = rr[0][2] + rr[1][2] + rr[2][2] + rr[3][2];
        float Se = rr[0][3] + rr[1][3] + rr[2][3] + rr[3][3];
        float diffusion = Sd * (1.0f / 49152.0f);
        float cd        = 0.5f * (Sl + Sr) * (1.0f / 16384.0f);
        float emd       = Se * (1.0f / 16384.0f);
        out[0] = diffusion + 0.1f * cd + 0.05f * emd;
    }
}

extern "C" void kernel_launch(void* const* d_in, const int* in_sizes, int n_in,
                              void* d_out, int out_size, void* d_ws, size_t ws_size,
                              hipStream_t stream) {
    const float* npred  = (const float*)d_in[0];
    const float* ntgt   = (const float*)d_in[1];
    const float* pp     = (const float*)d_in[2];
    const float* tp     = (const float*)d_in[3];
    const int*   assign = (const int*)d_in[4];
    float* ws  = (float*)d_ws;
    float* out = (float*)d_out;

    hipLaunchKernelGGL(kMain, dim3(512), dim3(256), 0, stream, npred, ntgt, pp, tp, assign, ws);
    hipLaunchKernelGGL(kC,    dim3(1),   dim3(256), 0, stream, ws, out);
}

// Round 7
// 12.888 us; speedup vs baseline: 1.5919x; 1.1882x over previous
//
#include <hip/hip_runtime.h>
#include <math.h>

// Problem constants: B=16, N=1024, D=3
#define NPTS  1024
#define EPSF  1e-8f

// ws layout (floats):
//   [0, 512)    chamfer partial per block (even bid = dl, odd bid = dr)
//   [512, 1024) side partial per block (even bid = diffusion, odd bid = emd)
#define OFF_PC 0
#define OFF_PS 512

__device__ __forceinline__ float clampf(float v, float lo, float hi) {
    return fminf(fmaxf(v, lo), hi);
}

// Main kernel: chamfer (register row-blocked) + side work.  [R4 config]
// grid = 512: dir = bid&1; rest = bid>>1 = batch*16 + 64-row chunk.
// Threads: s = tid&15 (candidate strip of 64), g = tid>>4 (row group of 4).
// LDS: second cloud, padded slot(j) = j + (j>>6) so strip s reads sec[65s+k]
// (linear in k; banks (4(s+k))%32 -> 8 groups x 2 addrs = free 2-way).
__global__ __launch_bounds__(256) void kMain(
    const float* __restrict__ npred, const float* __restrict__ ntgt,
    const float* __restrict__ pp,    const float* __restrict__ tp,
    const int*   __restrict__ assign, float* __restrict__ ws) {
    const int bid  = blockIdx.x;
    const int dir  = bid & 1;
    const int rest = bid >> 1;
    const int b    = rest >> 4;
    const int c    = rest & 15;
    const int tid  = threadIdx.x;

    __shared__ float4 sec[NPTS + 16];   // 1040 float4 = 16640 B

    const float* secSrc = dir ? pp : tp;
    const float* firSrc = dir ? tp : pp;

    // Stage + clip + normalize second cloud into padded slots.
    const float* sbase = secSrc + b * 3072;
    #pragma unroll
    for (int m = 0; m < 4; ++m) {
        int q = (m << 8) + tid;
        float x = sbase[3 * q], y = sbase[3 * q + 1], z = sbase[3 * q + 2];
        x = clampf(x, -1.f, 1.f); y = clampf(y, -1.f, 1.f); z = clampf(z, -1.f, 1.f);
        float n = fmaxf(sqrtf(x * x + y * y + z * z), EPSF);
        float r = 1.0f / n;
        sec[q + (q >> 6)] = make_float4(x * r, y * r, z * r, 0.f);
    }

    // Side work (overlaps staging).
    float side = 0.f;
    if (dir == 0) {
        if (tid < 48) {   // diffusion: 48 float4 per dir0-block
            int idx = rest * 48 + tid;
            float4 a  = ((const float4*)npred)[idx];
            float4 bb = ((const float4*)ntgt)[idx];
            float d0 = a.x - bb.x, d1 = a.y - bb.y, d2 = a.z - bb.z, d3 = a.w - bb.w;
            side = d0 * d0 + d1 * d1 + d2 * d2 + d3 * d3;
        }
    } else {
        if (tid < 64) {   // EMD: 64 points per dir1-block
            int p    = rest * 64 + tid;
            int base = 3 * p;
            float px = pp[base], py = pp[base + 1], pz = pp[base + 2];
            int bb = p >> 10;
            int a  = assign[p];
            int qb = 3 * ((bb << 10) + a);
            float mx = tp[qb], my = tp[qb + 1], mz = tp[qb + 2];
            float ex = clampf(px, -2.f, 2.f) - clampf(mx, -2.f, 2.f);
            float ey = clampf(py, -2.f, 2.f) - clampf(my, -2.f, 2.f);
            float ez = clampf(pz, -2.f, 2.f) - clampf(mz, -2.f, 2.f);
            side = fmaxf(sqrtf(ex * ex + ey * ey + ez * ez), EPSF);
        }
    }

    // My 4 rows: rows c*64 + g*4 .. +3 -> 12 consecutive floats, 16B-aligned.
    const int s = tid & 15;
    const int g = tid >> 4;
    const float4* fb4 = (const float4*)(firSrc + b * 3072 + 192 * c + 12 * g);
    float4 ra = fb4[0];   // p0.xyz p1.x
    float4 rb = fb4[1];   // p1.yz  p2.xy
    float4 rc = fb4[2];   // p2.z   p3.xyz

    float fx0, fy0, fz0, fx1, fy1, fz1, fx2, fy2, fz2, fx3, fy3, fz3;
    {
        float x, y, z, n, r;
        x = clampf(ra.x,-1.f,1.f); y = clampf(ra.y,-1.f,1.f); z = clampf(ra.z,-1.f,1.f);
        n = fmaxf(sqrtf(x*x+y*y+z*z), EPSF); r = 1.f/n; fx0=x*r; fy0=y*r; fz0=z*r;
        x = clampf(ra.w,-1.f,1.f); y = clampf(rb.x,-1.f,1.f); z = clampf(rb.y,-1.f,1.f);
        n = fmaxf(sqrtf(x*x+y*y+z*z), EPSF); r = 1.f/n; fx1=x*r; fy1=y*r; fz1=z*r;
        x = clampf(rb.z,-1.f,1.f); y = clampf(rb.w,-1.f,1.f); z = clampf(rc.x,-1.f,1.f);
        n = fmaxf(sqrtf(x*x+y*y+z*z), EPSF); r = 1.f/n; fx2=x*r; fy2=y*r; fz2=z*r;
        x = clampf(rc.y,-1.f,1.f); y = clampf(rc.z,-1.f,1.f); z = clampf(rc.w,-1.f,1.f);
        n = fmaxf(sqrtf(x*x+y*y+z*z), EPSF); r = 1.f/n; fx3=x*r; fy3=y*r; fz3=z*r;
    }

    __syncthreads();

    // Scan my 64-candidate strip against 4 rows. min||a-b||^2 = 2-2*max(dot).
    const float4* srow = sec + 65 * s;
    float m0 = -4.f, m1 = -4.f, m2 = -4.f, m3 = -4.f;
    #pragma unroll 8
    for (int k = 0; k < 64; ++k) {
        float4 g4 = srow[k];
        m0 = fmaxf(m0, fmaf(fx0, g4.x, fmaf(fy0, g4.y, fz0 * g4.z)));
        m1 = fmaxf(m1, fmaf(fx1, g4.x, fmaf(fy1, g4.y, fz1 * g4.z)));
        m2 = fmaxf(m2, fmaf(fx2, g4.x, fmaf(fy2, g4.y, fz2 * g4.z)));
        m3 = fmaxf(m3, fmaf(fx3, g4.x, fmaf(fy3, g4.y, fz3 * g4.z)));
    }
    // Reduce over the 16 strip-lanes (contiguous within each 16-lane group).
    #pragma unroll
    for (int o = 1; o < 16; o <<= 1) {
        m0 = fmaxf(m0, __shfl_xor(m0, o, 64));
        m1 = fmaxf(m1, __shfl_xor(m1, o, 64));
        m2 = fmaxf(m2, __shfl_xor(m2, o, 64));
        m3 = fmaxf(m3, __shfl_xor(m3, o, 64));
    }

    float val = 0.f;
    if (s == 0) {
        float mm[4] = { m0, m1, m2, m3 };
        #pragma unroll
        for (int r = 0; r < 4; ++r) {
            float ss   = fmaxf(2.f - 2.f * mm[r], 0.f);
            float dist = fmaxf(sqrtf(ss), EPSF);
            float ld   = clampf(logf(dist + EPSF), -10.f, 10.f);
            val += expf(ld);
        }
    }

    // Deterministic block reduction of (val, side) -> ws partials.
    for (int o = 32; o; o >>= 1) {
        val  += __shfl_down(val,  o, 64);
        side += __shfl_down(side, o, 64);
    }
    __shared__ float sv[4], sw[4];
    int w = tid >> 6;
    if ((tid & 63) == 0) { sv[w] = val; sw[w] = side; }
    __syncthreads();
    if (tid == 0) {
        ws[OFF_PC + bid] = sv[0] + sv[1] + sv[2] + sv[3];
        ws[OFF_PS + bid] = sw[0] + sw[1] + sw[2] + sw[3];
    }
}

// Final deterministic combine.
__global__ __launch_bounds__(256) void kC(const float* __restrict__ ws,
                                          float* __restrict__ out) {
    const int tid = threadIdx.x;
    float dl = ws[OFF_PC + 2 * tid];
    float dr = ws[OFF_PC + 2 * tid + 1];
    float sd = ws[OFF_PS + 2 * tid];
    float se = ws[OFF_PS + 2 * tid + 1];

    for (int o = 32; o; o >>= 1) {
        dl += __shfl_down(dl, o, 64);
        dr += __shfl_down(dr, o, 64);
        sd += __shfl_down(sd, o, 64);
        se += __shfl_down(se, o, 64);
    }
    __shared__ float rr[4][4];
    int w = tid >> 6;
    if ((tid & 63) == 0) { rr[w][0] = dl; rr[w][1] = dr; rr[w][2] = sd; rr[w][3] = se; }
    __syncthreads();
    if (tid == 0) {
        float Sl = rr[0][0] + rr[1][0] + rr[2][0] + rr[3][0];
        float Sr = rr[0][1] + rr[1][1] + rr[2][1] + rr[3][1];
        float Sd = rr[0][2] + rr[1][2] + rr[2][2] + rr[3][2];
        float Se = rr[0][3] + rr[1][3] + rr[2][3] + rr[3][3];
        float diffusion = Sd * (1.0f / 49152.0f);
        float cd        = 0.5f * (Sl + Sr) * (1.0f / 16384.0f);
        float emd       = Se * (1.0f / 16384.0f);
        out[0] = diffusion + 0.1f * cd + 0.05f * emd;
    }
}

extern "C" void kernel_launch(void* const* d_in, const int* in_sizes, int n_in,
                              void* d_out, int out_size, void* d_ws, size_t ws_size,
                              hipStream_t stream) {
    const float* npred  = (const float*)d_in[0];
    const float* ntgt   = (const float*)d_in[1];
    const float* pp     = (const float*)d_in[2];
    const float* tp     = (const float*)d_in[3];
    const int*   assign = (const int*)d_in[4];
    float* ws  = (float*)d_ws;
    float* out = (float*)d_out;

    hipLaunchKernelGGL(kMain, dim3(512), dim3(256), 0, stream, npred, ntgt, pp, tp, assign, ws);
    hipLaunchKernelGGL(kC,    dim3(1),   dim3(256), 0, stream, ws, out);
}